// Round 15
// baseline (302.845 us; speedup 1.0000x reference)
//
#include <hip/hip_runtime.h>
#include <hip/hip_bf16.h>
#include <stdint.h>

typedef _Float16 fp16_t;
typedef __attribute__((ext_vector_type(8))) _Float16 fp16x8;
typedef __attribute__((ext_vector_type(4))) _Float16 fp16x4;
typedef __attribute__((ext_vector_type(2))) _Float16 fp16x2;
typedef __attribute__((ext_vector_type(4))) float f32x4;

#define WIN 512
#define NG 64

__device__ __forceinline__ void gload16(const void* g, void* l) {
    __builtin_amdgcn_global_load_lds((const __attribute__((address_space(1))) void*)g,
                                     (__attribute__((address_space(3))) void*)l, 16, 0, 0);
}

__device__ __forceinline__ void wait_vm8() { asm volatile("s_waitcnt vmcnt(8)" ::: "memory"); }
__device__ __forceinline__ void wait_vm6() { asm volatile("s_waitcnt vmcnt(6)" ::: "memory"); }
__device__ __forceinline__ void wait_vm0() { asm volatile("s_waitcnt vmcnt(0)" ::: "memory"); }

// ---------------- transpose core (caller-provided LDS >= 8448B) ----------------
__device__ __forceinline__ void tr_tile_s(char* sb, const float* __restrict__ src, int C,
                                          int srow, int scol,
                                          fp16_t* __restrict__ out, int R, int orow) {
    fp16_t (*t)[66] = (fp16_t(*)[66])sb;
    int tid = threadIdx.x;
    int tx = tid & 15, ty = tid >> 4;
#pragma unroll
    for (int j = 0; j < 4; ++j) {
        int r = ty + j * 16;
        float4 v = *(const float4*)&src[(size_t)(srow + r) * C + scol + tx * 4];
        fp16x2 a = { (fp16_t)v.x, (fp16_t)v.y };
        fp16x2 b = { (fp16_t)v.z, (fp16_t)v.w };
        *(fp16x2*)&t[r][tx * 4] = a;
        *(fp16x2*)&t[r][tx * 4 + 2] = b;
    }
    __syncthreads();
#pragma unroll
    for (int jj = 0; jj < 4; ++jj) {
        int c = ty + jj * 16;
        fp16x4 o = { t[tx * 4 + 0][c], t[tx * 4 + 1][c], t[tx * 4 + 2][c], t[tx * 4 + 3][c] };
        *(fp16x4*)&out[(size_t)(orow + c) * R + srow + tx * 4] = o;
    }
}

// ---- prep: qkv-weight transpose (b<1536) + RMSNorm rows (b in [1536,3584)) ----
__global__ __launch_bounds__(256) void prep_kernel(const float* __restrict__ wq,
                                                   const float* __restrict__ wk,
                                                   const float* __restrict__ wv,
                                                   fp16_t* __restrict__ wqkvT,
                                                   const float* __restrict__ x,
                                                   const float* __restrict__ g,
                                                   fp16_t* __restrict__ hout) {
    __shared__ __align__(16) char sbuf[8448];
    int b = blockIdx.x;
    if (b < 1536) {
        int bx = b % 48, by = b / 48;
        int n0 = bx * 64, k0 = by * 64;
        const float* src; int C, c0;
        if (n0 < 2048)      { src = wq; C = 2048; c0 = n0; }
        else if (n0 < 2560) { src = wk; C = 512;  c0 = n0 - 2048; }
        else                { src = wv; C = 512;  c0 = n0 - 2560; }
        tr_tile_s(sbuf, src, C, k0, c0, wqkvT, 2048, n0);
        return;
    }
    int row = b - 1536;
    int tid = threadIdx.x;
    const float4* rp = (const float4*)(x + (size_t)row * 2048);
    float4 v0 = rp[tid], v1 = rp[tid + 256];
    float ss = v0.x * v0.x + v0.y * v0.y + v0.z * v0.z + v0.w * v0.w +
               v1.x * v1.x + v1.y * v1.y + v1.z * v1.z + v1.w * v1.w;
#pragma unroll
    for (int m = 1; m < 64; m <<= 1) ss += __shfl_xor(ss, m);
    float* red = (float*)sbuf;
    if ((tid & 63) == 0) red[tid >> 6] = ss;
    __syncthreads();
    ss = red[0] + red[1] + red[2] + red[3];
    float sc = rsqrtf(ss * (1.0f / 2048.0f) + 1e-6f);
    const float4* gp = (const float4*)g;
    float4 g0 = gp[tid], g1 = gp[tid + 256];
    fp16x4 o0 = { (fp16_t)(v0.x * sc * g0.x), (fp16_t)(v0.y * sc * g0.y),
                  (fp16_t)(v0.z * sc * g0.z), (fp16_t)(v0.w * sc * g0.w) };
    fp16x4 o1 = { (fp16_t)(v1.x * sc * g1.x), (fp16_t)(v1.y * sc * g1.y),
                  (fp16_t)(v1.z * sc * g1.z), (fp16_t)(v1.w * sc * g1.w) };
    *(fp16x4*)(hout + (size_t)row * 2048 + tid * 4) = o0;
    *(fp16x4*)(hout + (size_t)row * 2048 + 1024 + tid * 4) = o1;
}

// ---------------- RMSNorm: fp32 [2048][2048] -> fp16 ----------------
__global__ __launch_bounds__(256) void rmsnorm_kernel(const float* __restrict__ in,
                                                      const float* __restrict__ g,
                                                      fp16_t* __restrict__ out) {
    int row = blockIdx.x;
    int tid = threadIdx.x;
    const float4* rp = (const float4*)(in + (size_t)row * 2048);
    float4 v0 = rp[tid], v1 = rp[tid + 256];
    float ss = v0.x * v0.x + v0.y * v0.y + v0.z * v0.z + v0.w * v0.w +
               v1.x * v1.x + v1.y * v1.y + v1.z * v1.z + v1.w * v1.w;
#pragma unroll
    for (int m = 1; m < 64; m <<= 1) ss += __shfl_xor(ss, m);
    __shared__ float red[4];
    if ((tid & 63) == 0) red[tid >> 6] = ss;
    __syncthreads();
    ss = red[0] + red[1] + red[2] + red[3];
    float sc = rsqrtf(ss * (1.0f / 2048.0f) + 1e-6f);
    const float4* gp = (const float4*)g;
    float4 g0 = gp[tid], g1 = gp[tid + 256];
    fp16x4 o0 = { (fp16_t)(v0.x * sc * g0.x), (fp16_t)(v0.y * sc * g0.y),
                  (fp16_t)(v0.z * sc * g0.z), (fp16_t)(v0.w * sc * g0.w) };
    fp16x4 o1 = { (fp16_t)(v1.x * sc * g1.x), (fp16_t)(v1.y * sc * g1.y),
                  (fp16_t)(v1.z * sc * g1.z), (fp16_t)(v1.w * sc * g1.w) };
    *(fp16x4*)(out + (size_t)row * 2048 + tid * 4) = o0;
    *(fp16x4*)(out + (size_t)row * 2048 + 1024 + tid * 4) = o1;
}

// ---------------- GEMM core (BM=128, BN=128) ----------------
#define BM 128
#define BN 128
#define BKK 64

struct GemmCore {
    int tid, lane, wid, lo, hi, wr, wc;
    int arow[4], ascb[4];
    __device__ __forceinline__ void init(int t) {
        tid = t; lane = t & 63; wid = t >> 6;
        lo = lane & 15; hi = lane >> 4;
        wr = (wid >> 1) * 64; wc = (wid & 1) * 64;
#pragma unroll
        for (int p = 0; p < 4; ++p) {
            int idx = (wid * 4 + p) * 64 + lane;
            int row = idx >> 3;
            int cb = (idx & 7) << 4;
            arow[p] = row;
            ascb[p] = cb ^ ((row & 7) << 4);
        }
    }
    __device__ __forceinline__ void stage(char* buf, const fp16_t* A, const fp16_t* Bt,
                                          int brow, int bcol, int lda, int ldb, int kb) {
        char* As = buf;
        char* Bs = buf + 16384;
#pragma unroll
        for (int p = 0; p < 4; ++p) {
            int ci = wid * 4 + p;
            gload16((const char*)A + ((size_t)(brow + arow[p]) * lda + kb) * 2 + ascb[p],
                    As + ci * 1024);
            gload16((const char*)Bt + ((size_t)(bcol + arow[p]) * ldb + kb) * 2 + ascb[p],
                    Bs + ci * 1024);
        }
    }
    __device__ __forceinline__ void compute(const char* buf, f32x4 (&acc)[4][4]) {
        const char* As = buf;
        const char* Bs = buf + 16384;
#pragma unroll
        for (int kc = 0; kc < 2; ++kc) {
            fp16x8 af[4], bfr[4];
            int boff = kc * 64 + hi * 16;
#pragma unroll
            for (int m = 0; m < 4; ++m) {
                int row = wr + m * 16 + lo;
                af[m] = *(const fp16x8*)(As + row * 128 + (boff ^ ((row & 7) << 4)));
            }
#pragma unroll
            for (int n = 0; n < 4; ++n) {
                int row = wc + n * 16 + lo;
                bfr[n] = *(const fp16x8*)(Bs + row * 128 + (boff ^ ((row & 7) << 4)));
            }
#pragma unroll
            for (int m = 0; m < 4; ++m)
#pragma unroll
                for (int n = 0; n < 4; ++n)
                    acc[m][n] = __builtin_amdgcn_mfma_f32_16x16x32_f16(af[m], bfr[n], acc[m][n], 0, 0, 0);
        }
    }
};

// qkv GEMM (b<384, flattened) + wo/w1/w3/w2 transposes (b>=384) in ONE dispatch.
__global__ __launch_bounds__(256, 2) void gemm_qkv_tr(const fp16_t* __restrict__ A,
                                                      const fp16_t* __restrict__ Bt,
                                                      fp16_t* __restrict__ Cout,
                                                      fp16_t* __restrict__ vT,
                                                      int M, int N, int K,
                                                      const float* __restrict__ wo,
                                                      const float* __restrict__ w1,
                                                      const float* __restrict__ w3,
                                                      const float* __restrict__ w2,
                                                      fp16_t* __restrict__ woT,
                                                      fp16_t* __restrict__ w1T,
                                                      fp16_t* __restrict__ w3T,
                                                      fp16_t* __restrict__ w2T) {
    __shared__ __align__(16) char smem[2][32768];
    int b = blockIdx.x;
    if (b >= 384) {
        int r = b - 384;
        if (r < 1024) {
            int bx = r % 32, by = r / 32;
            tr_tile_s((char*)smem, wo, 2048, by * 64, bx * 64, woT, 2048, bx * 64);
        } else if (r < 3840) {
            r -= 1024;
            int bx = r % 88, by = r / 88;
            tr_tile_s((char*)smem, w1, 5632, by * 64, bx * 64, w1T, 2048, bx * 64);
        } else if (r < 6656) {
            r -= 3840;
            int bx = r % 88, by = r / 88;
            tr_tile_s((char*)smem, w3, 5632, by * 64, bx * 64, w3T, 2048, bx * 64);
        } else {
            r -= 6656;
            int bx = r % 32, by = r / 32;
            tr_tile_s((char*)smem, w2, 2048, by * 64, bx * 64, w2T, 5632, bx * 64);
        }
        return;
    }

    int bx = b % 24, by = b / 24;
    GemmCore g;
    g.init(threadIdx.x);
    int brow = by * BM, bcol = bx * BN;
    int nK = K / BKK;

    f32x4 acc[4][4] = {};
    g.stage(smem[0], A, Bt, brow, bcol, K, K, 0);
    for (int kt = 0; kt < nK; ++kt) {
        if (kt + 1 < nK) {
            g.stage(smem[(kt + 1) & 1], A, Bt, brow, bcol, K, K, (kt + 1) * BKK);
            wait_vm8();
        } else {
            wait_vm0();
        }
        __builtin_amdgcn_s_barrier();
        __builtin_amdgcn_sched_barrier(0);
        g.compute(smem[kt & 1], acc);
        __builtin_amdgcn_s_barrier();
    }

    if (bx < 20) {
        float* sq = (float*)smem;
        bool isq = bx < 16;
#pragma unroll
        for (int m = 0; m < 4; ++m)
#pragma unroll
            for (int r = 0; r < 4; ++r) {
                float s = 0.f;
#pragma unroll
                for (int n = 0; n < 4; ++n) s += acc[m][n][r] * acc[m][n][r];
                s += __shfl_xor(s, 1); s += __shfl_xor(s, 2);
                s += __shfl_xor(s, 4); s += __shfl_xor(s, 8);
                if (g.lo == 0) sq[g.wid * 64 + m * 16 + g.hi * 4 + r] = s;
            }
        __syncthreads();
#pragma unroll
        for (int m = 0; m < 4; ++m)
#pragma unroll
            for (int r = 0; r < 4; ++r) {
                int rl = m * 16 + g.hi * 4 + r;
                float tot = sq[g.wid * 64 + rl] + sq[(g.wid ^ 1) * 64 + rl];
                float sc = rsqrtf(tot * (1.0f / 128.0f) + 1e-6f);
                if (isq) sc *= 0.08838834764831843f;
#pragma unroll
                for (int n = 0; n < 4; ++n) acc[m][n][r] *= sc;
            }
#pragma unroll
        for (int m = 0; m < 4; ++m) {
            int grow0 = brow + g.wr + m * 16 + g.hi * 4;
#pragma unroll
            for (int n = 0; n < 4; ++n) {
                int gcol = bcol + g.wc + n * 16 + g.lo;
#pragma unroll
                for (int r = 0; r < 4; ++r)
                    Cout[(size_t)(grow0 + r) * N + gcol] = (fp16_t)acc[m][n][r];
            }
        }
    } else {
        // v head: transposed write into vT [512][2048]. v region starts at col 2560.
#pragma unroll
        for (int m = 0; m < 4; ++m) {
            int gcol0 = brow + g.wr + m * 16 + g.hi * 4;
#pragma unroll
            for (int n = 0; n < 4; ++n) {
                int vrow = bcol + g.wc + n * 16 + g.lo - 2560;
                fp16x4 o = { (fp16_t)acc[m][n][0], (fp16_t)acc[m][n][1],
                             (fp16_t)acc[m][n][2], (fp16_t)acc[m][n][3] };
                *(fp16x4*)&vT[(size_t)vrow * 2048 + gcol0] = o;
            }
        }
    }
}

// BN=64 GEMM with fused residual epilogue; XCD-chunked swizzle (512 blocks: each XCD gets
// 2 contiguous by-rows x 32 bx -> its 2 A-panels stay L2-resident).
__global__ __launch_bounds__(256, 2) void gemm_bt64_resid(const fp16_t* __restrict__ A,
                                                          const fp16_t* __restrict__ Bt,
                                                          float* __restrict__ Cout,
                                                          const float* __restrict__ resid,
                                                          int M, int N, int K) {
    __shared__ __align__(16) char smem[2][24576];
    int bo = blockIdx.x;                  // 512 blocks flat
    int L = (bo % 8) * 64 + bo / 8;       // bijective (512 % 8 == 0)
    int bxb = L % 32, byb = L / 32;
    int tid = threadIdx.x, lane = tid & 63, wid = tid >> 6;
    int lo = lane & 15, hi = lane >> 4;
    int wr = (wid >> 1) * 64, wc = (wid & 1) * 32;
    int brow = byb * 128, bcol = bxb * 64;
    int nK = K / BKK;

    int arow[4], ascb[4];
#pragma unroll
    for (int p = 0; p < 4; ++p) {
        int idx = (wid * 4 + p) * 64 + lane;
        int row = idx >> 3;
        int cb = (idx & 7) << 4;
        arow[p] = row;
        ascb[p] = cb ^ ((row & 7) << 4);
    }
    int brow_[2], bscb[2];
#pragma unroll
    for (int p = 0; p < 2; ++p) {
        int idx = (wid * 2 + p) * 64 + lane;
        int row = idx >> 3;
        int cb = (idx & 7) << 4;
        brow_[p] = row;
        bscb[p] = cb ^ ((row & 7) << 4);
    }

    auto stage = [&](char* buf, int kb) {
        char* As = buf;
        char* Bs = buf + 16384;
#pragma unroll
        for (int p = 0; p < 4; ++p)
            gload16((const char*)A + ((size_t)(brow + arow[p]) * K + kb) * 2 + ascb[p],
                    As + (wid * 4 + p) * 1024);
#pragma unroll
        for (int p = 0; p < 2; ++p)
            gload16((const char*)Bt + ((size_t)(bcol + brow_[p]) * K + kb) * 2 + bscb[p],
                    Bs + (wid * 2 + p) * 1024);
    };

    f32x4 acc[4][2] = {};
    stage(smem[0], 0);
    for (int kt = 0; kt < nK; ++kt) {
        if (kt + 1 < nK) {
            stage(smem[(kt + 1) & 1], (kt + 1) * BKK);
            wait_vm6();
        } else {
            wait_vm0();
        }
        __builtin_amdgcn_s_barrier();
        __builtin_amdgcn_sched_barrier(0);
        const char* As = smem[kt & 1];
        const char* Bs = As + 16384;
#pragma unroll
        for (int kc = 0; kc < 2; ++kc) {
            fp16x8 af[4], bfr[2];
            int boff = kc * 64 + hi * 16;
#pragma unroll
            for (int m = 0; m < 4; ++m) {
                int row = wr + m * 16 + lo;
                af[m] = *(const fp16x8*)(As + row * 128 + (boff ^ ((row & 7) << 4)));
            }
#pragma unroll
            for (int n = 0; n < 2; ++n) {
                int row = wc + n * 16 + lo;
                bfr[n] = *(const fp16x8*)(Bs + row * 128 + (boff ^ ((row & 7) << 4)));
            }
#pragma unroll
            for (int m = 0; m < 4; ++m)
#pragma unroll
                for (int n = 0; n < 2; ++n)
                    acc[m][n] = __builtin_amdgcn_mfma_f32_16x16x32_f16(af[m], bfr[n], acc[m][n], 0, 0, 0);
        }
        __builtin_amdgcn_s_barrier();
    }

#pragma unroll
    for (int m = 0; m < 4; ++m) {
        int grow0 = brow + wr + m * 16 + hi * 4;
#pragma unroll
        for (int n = 0; n < 2; ++n) {
            int gcol = bcol + wc + n * 16 + lo;
#pragma unroll
            for (int r = 0; r < 4; ++r) {
                size_t gidx = (size_t)(grow0 + r) * N + gcol;
                Cout[gidx] = acc[m][n][r] + resid[gidx];
            }
        }
    }
}

// Fused FFN up, half-width dual-acc; XCD-chunked swizzle (1408 blocks: each XCD gets
// 2 contiguous by-rows x 88 bx).
__global__ __launch_bounds__(256, 2) void gemm_u1u3_half(const fp16_t* __restrict__ A,
                                                         const fp16_t* __restrict__ Bt1,
                                                         const fp16_t* __restrict__ Bt3,
                                                         fp16_t* __restrict__ G,
                                                         int M, int N, int K) {
    __shared__ __align__(16) char smem[2][32768];
    int bo = blockIdx.x;                   // 1408 flat
    int L = (bo % 8) * 176 + bo / 8;       // bijective (1408 % 8 == 0)
    int bxb = L % 88, byb = L / 88;
    int tid = threadIdx.x, lane = tid & 63, wid = tid >> 6;
    int lo = lane & 15, hi = lane >> 4;
    int wr = (wid >> 1) * 64, wc = (wid & 1) * 32;
    int brow = byb * 128, bcol = bxb * 64;
    int nK = K / BKK;

    int arow[4], ascb[4];
#pragma unroll
    for (int p = 0; p < 4; ++p) {
        int idx = (wid * 4 + p) * 64 + lane;
        int row = idx >> 3;
        int cb = (idx & 7) << 4;
        arow[p] = row;
        ascb[p] = cb ^ ((row & 7) << 4);
    }
    int brow_[2], bscb[2];
#pragma unroll
    for (int p = 0; p < 2; ++p) {
        int idx = (wid * 2 + p) * 64 + lane;
        int row = idx >> 3;
        int cb = (idx & 7) << 4;
        brow_[p] = row;
        bscb[p] = cb ^ ((row & 7) << 4);
    }

    auto stage = [&](char* buf, int kb) {
        char* As = buf;
        char* B1s = buf + 16384;
        char* B3s = buf + 24576;
#pragma unroll
        for (int p = 0; p < 4; ++p)
            gload16((const char*)A + ((size_t)(brow + arow[p]) * K + kb) * 2 + ascb[p],
                    As + (wid * 4 + p) * 1024);
#pragma unroll
        for (int p = 0; p < 2; ++p) {
            gload16((const char*)Bt1 + ((size_t)(bcol + brow_[p]) * K + kb) * 2 + bscb[p],
                    B1s + (wid * 2 + p) * 1024);
            gload16((const char*)Bt3 + ((size_t)(bcol + brow_[p]) * K + kb) * 2 + bscb[p],
                    B3s + (wid * 2 + p) * 1024);
        }
    };

    f32x4 acc1[4][2] = {}, acc3[4][2] = {};
    stage(smem[0], 0);
    for (int kt = 0; kt < nK; ++kt) {
        if (kt + 1 < nK) {
            stage(smem[(kt + 1) & 1], (kt + 1) * BKK);
            wait_vm8();
        } else {
            wait_vm0();
        }
        __builtin_amdgcn_s_barrier();
        __builtin_amdgcn_sched_barrier(0);
        const char* As = smem[kt & 1];
        const char* B1s = As + 16384;
        const char* B3s = As + 24576;
#pragma unroll
        for (int kc = 0; kc < 2; ++kc) {
            fp16x8 af[4], b1f[2], b3f[2];
            int boff = kc * 64 + hi * 16;
#pragma unroll
            for (int m = 0; m < 4; ++m) {
                int row = wr + m * 16 + lo;
                af[m] = *(const fp16x8*)(As + row * 128 + (boff ^ ((row & 7) << 4)));
            }
#pragma unroll
            for (int n = 0; n < 2; ++n) {
                int row = wc + n * 16 + lo;
                int o = row * 128 + (boff ^ ((row & 7) << 4));
                b1f[n] = *(const fp16x8*)(B1s + o);
                b3f[n] = *(const fp16x8*)(B3s + o);
            }
#pragma unroll
            for (int m = 0; m < 4; ++m)
#pragma unroll
                for (int n = 0; n < 2; ++n) {
                    acc1[m][n] = __builtin_amdgcn_mfma_f32_16x16x32_f16(af[m], b1f[n], acc1[m][n], 0, 0, 0);
                    acc3[m][n] = __builtin_amdgcn_mfma_f32_16x16x32_f16(af[m], b3f[n], acc3[m][n], 0, 0, 0);
                }
        }
        __builtin_amdgcn_s_barrier();
    }

#pragma unroll
    for (int m = 0; m < 4; ++m) {
        int grow0 = brow + wr + m * 16 + hi * 4;
#pragma unroll
        for (int n = 0; n < 2; ++n) {
            int gcol = bcol + wc + n * 16 + lo;
#pragma unroll
            for (int r = 0; r < 4; ++r) {
                float u = acc1[m][n][r];
                float val = (u / (1.0f + __expf(-u))) * acc3[m][n][r];
                G[(size_t)(grow0 + r) * N + gcol] = (fp16_t)val;
            }
        }
    }
}

// ---------------- Flash attention (standalone, 512 blocks, pipelined) ----------------
__global__ __launch_bounds__(256, 2) void attn_kernel(const fp16_t* __restrict__ qkv,
                                                      const fp16_t* __restrict__ vT,
                                                      fp16_t* __restrict__ o) {
    __shared__ __align__(16) char smem[2 * 32768 + 4 * 2304];
    char* Ps = smem + 65536;

    int t = blockIdx.x, qh = blockIdx.y;
    int kvh = qh >> 2;
    int qs = t * 64;
    int tid = threadIdx.x, lane = tid & 63, wid = tid >> 6;
    int lo = lane & 15, hi = lane >> 4;

    fp16x8 qf[4];
    {
        const fp16_t* qptr = qkv + (size_t)(qs + wid * 16 + lo) * 3072 + qh * 128 + hi * 8;
#pragma unroll
        for (int kc = 0; kc < 4; ++kc) qf[kc] = *(const fp16x8*)(qptr + kc * 32);
    }

    f32x4 oacc[8] = {};
    float m_r[4], l_r[4];
#pragma unroll
    for (int r = 0; r < 4; ++r) { m_r[r] = -1e30f; l_r[r] = 0.0f; }

    int lot = qs - (WIN - 1);
    int jt_lo = lot <= 0 ? 0 : (lot >> 6);
    int nt = (jt_lo > 0) ? (t - jt_lo + 2) : (t + 1);

    int kci = wid * 4, idxb = lane;
    auto stagekv = [&](char* buf, int js) {
        char* Ks = buf;
        char* VTs = buf + 16384;
#pragma unroll
        for (int p = 0; p < 4; ++p) {
            int ci = kci + p;
            int idx = ci * 64 + idxb;
            int krow = idx >> 4;
            int kcb = (idx & 15) << 4;
            int kscb = kcb ^ ((krow & 7) << 4);
            gload16((const char*)qkv + ((size_t)(js + krow) * 3072 + 2048 + kvh * 128) * 2 + kscb,
                    Ks + ci * 1024);
            int vrow = idx >> 3;
            int vcb = (idx & 7) << 4;
            int vscb = vcb ^ ((vrow & 7) << 4);
            gload16((const char*)vT + ((size_t)(kvh * 128 + vrow) * 2048 + js) * 2 + vscb,
                    VTs + ci * 1024);
        }
    };
    auto jt_of = [&](int ti) { return (jt_lo > 0) ? (ti == 0 ? 0 : jt_lo + ti - 1) : ti; };

    stagekv(smem, jt_of(0) * 64);

    for (int ti = 0; ti < nt; ++ti) {
        if (ti + 1 < nt) {
            stagekv(smem + ((ti + 1) & 1) * 32768, jt_of(ti + 1) * 64);
            wait_vm8();
        } else {
            wait_vm0();
        }
        __builtin_amdgcn_s_barrier();
        __builtin_amdgcn_sched_barrier(0);

        char* Ks = smem + (ti & 1) * 32768;
        char* VTs = Ks + 16384;
        int jt = jt_of(ti);
        int js = jt * 64;

        f32x4 s[4] = {};
        __builtin_amdgcn_s_setprio(1);
#pragma unroll
        for (int kc = 0; kc < 4; ++kc) {
#pragma unroll
            for (int jc = 0; jc < 4; ++jc) {
                int row = jc * 16 + lo;
                fp16x8 kf = *(const fp16x8*)(Ks + row * 256 + ((kc * 64 + hi * 16) ^ ((row & 7) << 4)));
                s[jc] = __builtin_amdgcn_mfma_f32_16x16x32_f16(qf[kc], kf, s[jc], 0, 0, 0);
            }
        }
        __builtin_amdgcn_s_setprio(0);

        float mt[4] = { -1e30f, -1e30f, -1e30f, -1e30f };
        bool full = (jt < t) && !((t >= 9) && (jt == t - 8));
        if (full) {
#pragma unroll
            for (int jc = 0; jc < 4; ++jc)
#pragma unroll
                for (int r = 0; r < 4; ++r) mt[r] = fmaxf(mt[r], s[jc][r]);
        } else {
#pragma unroll
            for (int jc = 0; jc < 4; ++jc) {
                int j = js + jc * 16 + lo;
#pragma unroll
                for (int r = 0; r < 4; ++r) {
                    int i = qs + wid * 16 + hi * 4 + r;
                    bool ok = (j <= i) && (((i - j) < WIN) || (j < NG) || (i < NG));
                    float sv = ok ? s[jc][r] : -1e30f;
                    s[jc][r] = sv;
                    mt[r] = fmaxf(mt[r], sv);
                }
            }
        }
#pragma unroll
        for (int m2 = 1; m2 <= 8; m2 <<= 1)
#pragma unroll
            for (int r = 0; r < 4; ++r) mt[r] = fmaxf(mt[r], __shfl_xor(mt[r], m2));
        float sf[4], psum[4];
#pragma unroll
        for (int r = 0; r < 4; ++r) {
            float mn = fmaxf(m_r[r], mt[r]);
            sf[r] = __expf(m_r[r] - mn);
            m_r[r] = mn;
            psum[r] = 0.0f;
        }
#pragma unroll
        for (int jc = 0; jc < 4; ++jc)
#pragma unroll
            for (int r = 0; r < 4; ++r) {
                float p = __expf(s[jc][r] - m_r[r]);
                s[jc][r] = p;
                psum[r] += p;
            }
#pragma unroll
        for (int m2 = 1; m2 <= 8; m2 <<= 1)
#pragma unroll
            for (int r = 0; r < 4; ++r) psum[r] += __shfl_xor(psum[r], m2);
#pragma unroll
        for (int r = 0; r < 4; ++r) l_r[r] = l_r[r] * sf[r] + psum[r];
#pragma unroll
        for (int nc = 0; nc < 8; ++nc)
#pragma unroll
            for (int r = 0; r < 4; ++r) oacc[nc][r] *= sf[r];

        char* Pb = Ps + wid * 2304;
#pragma unroll
        for (int jc = 0; jc < 4; ++jc)
#pragma unroll
            for (int r = 0; r < 4; ++r)
                *(fp16_t*)(Pb + (hi * 4 + r) * 144 + (jc * 16 + lo) * 2) = (fp16_t)s[jc][r];
        fp16x8 pa[2];
#pragma unroll
        for (int jc2 = 0; jc2 < 2; ++jc2)
            pa[jc2] = *(const fp16x8*)(Pb + lo * 144 + jc2 * 64 + hi * 16);

        __builtin_amdgcn_s_setprio(1);
#pragma unroll
        for (int jc2 = 0; jc2 < 2; ++jc2)
#pragma unroll
            for (int nc = 0; nc < 8; ++nc) {
                int row = nc * 16 + lo;
                fp16x8 vf = *(const fp16x8*)(VTs + row * 128 + ((jc2 * 64 + hi * 16) ^ ((row & 7) << 4)));
                oacc[nc] = __builtin_amdgcn_mfma_f32_16x16x32_f16(pa[jc2], vf, oacc[nc], 0, 0, 0);
            }
        __builtin_amdgcn_s_setprio(0);

        __builtin_amdgcn_s_barrier();
    }

#pragma unroll
    for (int r = 0; r < 4; ++r) {
        float inv = 1.0f / l_r[r];
        int orow = qs + wid * 16 + hi * 4 + r;
#pragma unroll
        for (int nc = 0; nc < 8; ++nc)
            o[(size_t)orow * 2048 + qh * 128 + nc * 16 + lo] = (fp16_t)(oacc[nc][r] * inv);
    }
}

// ---------------- host ----------------
extern "C" void kernel_launch(void* const* d_in, const int* in_sizes, int n_in,
                              void* d_out, int out_size, void* d_ws, size_t ws_size,
                              hipStream_t stream) {
    // setup_inputs() dict order: x, g_attn, g_ffn, wq, wk, wv, wo, w1, w3, w2
    const float* x = (const float*)d_in[0];
    const float* g_attn = (const float*)d_in[1];
    const float* g_ffn = (const float*)d_in[2];
    const float* wq = (const float*)d_in[3];
    const float* wk = (const float*)d_in[4];
    const float* wv = (const float*)d_in[5];
    const float* wo = (const float*)d_in[6];
    const float* w1 = (const float*)d_in[7];  // gate proj (D,F)
    const float* w3 = (const float*)d_in[8];  // up proj   (D,F)  <- dict order!
    const float* w2 = (const float*)d_in[9];  // down proj (F,D)  <- dict order!
    float* out = (float*)d_out;               // doubles as x1 buffer

    char* ws = (char*)d_ws;
    size_t off = 0;
    auto alloc = [&](size_t bytes) {
        char* p = ws + off;
        off += (bytes + 255) & ~(size_t)255;
        return p;
    };
    fp16_t* hbuf  = (fp16_t*)alloc(2048ull * 2048 * 2);  // h, then attn out o
    fp16_t* wqkvT = (fp16_t*)alloc(3072ull * 2048 * 2);
    fp16_t* woT   = (fp16_t*)alloc(2048ull * 2048 * 2);
    fp16_t* vTb   = (fp16_t*)alloc(512ull * 2048 * 2);
    fp16_t* qkv   = (fp16_t*)alloc(2048ull * 3072 * 2);  // q|k (v direct to vTb), then h2
    fp16_t* gbuf  = (fp16_t*)alloc(2048ull * 5632 * 2);  // g = silu(u1)*u3
    fp16_t* w1T   = (fp16_t*)alloc(5632ull * 2048 * 2);
    fp16_t* w3T   = (fp16_t*)alloc(5632ull * 2048 * 2);
    fp16_t* w2T   = (fp16_t*)alloc(2048ull * 5632 * 2);
    if (off > ws_size) {  // diagnostic fallback: absmax ~= max|ref|
        hipMemsetAsync(d_out, 0, (size_t)out_size * 4, stream);
        return;
    }

    // prep: qkv-weight transpose + h = RMSNorm(x)*g_attn (one dispatch)
    prep_kernel<<<3584, 256, 0, stream>>>(wq, wk, wv, wqkvT, x, g_attn, hbuf);
    // qkv GEMM (384 blocks) co-scheduled with wo/w1/w3/w2 transposes
    gemm_qkv_tr<<<9856, 256, 0, stream>>>(hbuf, wqkvT, qkv, vTb, 2048, 3072, 2048,
                                          wo, w1, w3, w2, woT, w1T, w3T, w2T);
    // attention -> o (reuses hbuf)
    attn_kernel<<<dim3(32, 16), 256, 0, stream>>>(qkv, vTb, hbuf);
    // x1 = x + o @ wo  (XCD-chunked, fused residual, fp32 -> d_out)
    gemm_bt64_resid<<<512, 256, 0, stream>>>(hbuf, woT, out, x, 2048, 2048, 2048);
    // h2 = RMSNorm(x1) * g_ffn  (-> qkv buffer)
    rmsnorm_kernel<<<2048, 256, 0, stream>>>(out, g_ffn, qkv);
    // g = silu(h2@w1) * (h2@w3)  (XCD-chunked, 1408 blocks)
    gemm_u1u3_half<<<1408, 256, 0, stream>>>(qkv, w1T, w3T, gbuf, 2048, 5632, 2048);
    // out = x1 + g @ w2  (XCD-chunked, in-place on d_out)
    gemm_bt64_resid<<<512, 256, 0, stream>>>(gbuf, w2T, out, out, 2048, 2048, 5632);
}

// Round 16
// 279.891 us; speedup vs baseline: 1.0820x; 1.0820x over previous
//
#include <hip/hip_runtime.h>
#include <hip/hip_bf16.h>
#include <stdint.h>

typedef _Float16 fp16_t;
typedef __attribute__((ext_vector_type(8))) _Float16 fp16x8;
typedef __attribute__((ext_vector_type(4))) _Float16 fp16x4;
typedef __attribute__((ext_vector_type(2))) _Float16 fp16x2;
typedef __attribute__((ext_vector_type(4))) float f32x4;

#define WIN 512
#define NG 64

__device__ __forceinline__ void gload16(const void* g, void* l) {
    __builtin_amdgcn_global_load_lds((const __attribute__((address_space(1))) void*)g,
                                     (__attribute__((address_space(3))) void*)l, 16, 0, 0);
}

__device__ __forceinline__ void wait_vm8() { asm volatile("s_waitcnt vmcnt(8)" ::: "memory"); }
__device__ __forceinline__ void wait_vm6() { asm volatile("s_waitcnt vmcnt(6)" ::: "memory"); }
__device__ __forceinline__ void wait_vm0() { asm volatile("s_waitcnt vmcnt(0)" ::: "memory"); }

// ---------------- transpose core (caller-provided LDS >= 8448B) ----------------
__device__ __forceinline__ void tr_tile_s(char* sb, const float* __restrict__ src, int C,
                                          int srow, int scol,
                                          fp16_t* __restrict__ out, int R, int orow) {
    fp16_t (*t)[66] = (fp16_t(*)[66])sb;
    int tid = threadIdx.x;
    int tx = tid & 15, ty = tid >> 4;
#pragma unroll
    for (int j = 0; j < 4; ++j) {
        int r = ty + j * 16;
        float4 v = *(const float4*)&src[(size_t)(srow + r) * C + scol + tx * 4];
        fp16x2 a = { (fp16_t)v.x, (fp16_t)v.y };
        fp16x2 b = { (fp16_t)v.z, (fp16_t)v.w };
        *(fp16x2*)&t[r][tx * 4] = a;
        *(fp16x2*)&t[r][tx * 4 + 2] = b;
    }
    __syncthreads();
#pragma unroll
    for (int jj = 0; jj < 4; ++jj) {
        int c = ty + jj * 16;
        fp16x4 o = { t[tx * 4 + 0][c], t[tx * 4 + 1][c], t[tx * 4 + 2][c], t[tx * 4 + 3][c] };
        *(fp16x4*)&out[(size_t)(orow + c) * R + srow + tx * 4] = o;
    }
}

// ---- prep: qkv-weight transpose (b<1536) + RMSNorm rows (b in [1536,3584)) ----
__global__ __launch_bounds__(256) void prep_kernel(const float* __restrict__ wq,
                                                   const float* __restrict__ wk,
                                                   const float* __restrict__ wv,
                                                   fp16_t* __restrict__ wqkvT,
                                                   const float* __restrict__ x,
                                                   const float* __restrict__ g,
                                                   fp16_t* __restrict__ hout) {
    __shared__ __align__(16) char sbuf[8448];
    int b = blockIdx.x;
    if (b < 1536) {
        int bx = b % 48, by = b / 48;
        int n0 = bx * 64, k0 = by * 64;
        const float* src; int C, c0;
        if (n0 < 2048)      { src = wq; C = 2048; c0 = n0; }
        else if (n0 < 2560) { src = wk; C = 512;  c0 = n0 - 2048; }
        else                { src = wv; C = 512;  c0 = n0 - 2560; }
        tr_tile_s(sbuf, src, C, k0, c0, wqkvT, 2048, n0);
        return;
    }
    int row = b - 1536;
    int tid = threadIdx.x;
    const float4* rp = (const float4*)(x + (size_t)row * 2048);
    float4 v0 = rp[tid], v1 = rp[tid + 256];
    float ss = v0.x * v0.x + v0.y * v0.y + v0.z * v0.z + v0.w * v0.w +
               v1.x * v1.x + v1.y * v1.y + v1.z * v1.z + v1.w * v1.w;
#pragma unroll
    for (int m = 1; m < 64; m <<= 1) ss += __shfl_xor(ss, m);
    float* red = (float*)sbuf;
    if ((tid & 63) == 0) red[tid >> 6] = ss;
    __syncthreads();
    ss = red[0] + red[1] + red[2] + red[3];
    float sc = rsqrtf(ss * (1.0f / 2048.0f) + 1e-6f);
    const float4* gp = (const float4*)g;
    float4 g0 = gp[tid], g1 = gp[tid + 256];
    fp16x4 o0 = { (fp16_t)(v0.x * sc * g0.x), (fp16_t)(v0.y * sc * g0.y),
                  (fp16_t)(v0.z * sc * g0.z), (fp16_t)(v0.w * sc * g0.w) };
    fp16x4 o1 = { (fp16_t)(v1.x * sc * g1.x), (fp16_t)(v1.y * sc * g1.y),
                  (fp16_t)(v1.z * sc * g1.z), (fp16_t)(v1.w * sc * g1.w) };
    *(fp16x4*)(hout + (size_t)row * 2048 + tid * 4) = o0;
    *(fp16x4*)(hout + (size_t)row * 2048 + 1024 + tid * 4) = o1;
}

// ---------------- RMSNorm: fp32 [2048][2048] -> fp16 ----------------
__global__ __launch_bounds__(256) void rmsnorm_kernel(const float* __restrict__ in,
                                                      const float* __restrict__ g,
                                                      fp16_t* __restrict__ out) {
    int row = blockIdx.x;
    int tid = threadIdx.x;
    const float4* rp = (const float4*)(in + (size_t)row * 2048);
    float4 v0 = rp[tid], v1 = rp[tid + 256];
    float ss = v0.x * v0.x + v0.y * v0.y + v0.z * v0.z + v0.w * v0.w +
               v1.x * v1.x + v1.y * v1.y + v1.z * v1.z + v1.w * v1.w;
#pragma unroll
    for (int m = 1; m < 64; m <<= 1) ss += __shfl_xor(ss, m);
    __shared__ float red[4];
    if ((tid & 63) == 0) red[tid >> 6] = ss;
    __syncthreads();
    ss = red[0] + red[1] + red[2] + red[3];
    float sc = rsqrtf(ss * (1.0f / 2048.0f) + 1e-6f);
    const float4* gp = (const float4*)g;
    float4 g0 = gp[tid], g1 = gp[tid + 256];
    fp16x4 o0 = { (fp16_t)(v0.x * sc * g0.x), (fp16_t)(v0.y * sc * g0.y),
                  (fp16_t)(v0.z * sc * g0.z), (fp16_t)(v0.w * sc * g0.w) };
    fp16x4 o1 = { (fp16_t)(v1.x * sc * g1.x), (fp16_t)(v1.y * sc * g1.y),
                  (fp16_t)(v1.z * sc * g1.z), (fp16_t)(v1.w * sc * g1.w) };
    *(fp16x4*)(out + (size_t)row * 2048 + tid * 4) = o0;
    *(fp16x4*)(out + (size_t)row * 2048 + 1024 + tid * 4) = o1;
}

// ---------------- GEMM core (BM=128, BN=128) ----------------
#define BM 128
#define BN 128
#define BKK 64

struct GemmCore {
    int tid, lane, wid, lo, hi, wr, wc;
    int arow[4], ascb[4];
    __device__ __forceinline__ void init(int t) {
        tid = t; lane = t & 63; wid = t >> 6;
        lo = lane & 15; hi = lane >> 4;
        wr = (wid >> 1) * 64; wc = (wid & 1) * 64;
#pragma unroll
        for (int p = 0; p < 4; ++p) {
            int idx = (wid * 4 + p) * 64 + lane;
            int row = idx >> 3;
            int cb = (idx & 7) << 4;
            arow[p] = row;
            ascb[p] = cb ^ ((row & 7) << 4);
        }
    }
    __device__ __forceinline__ void stage(char* buf, const fp16_t* A, const fp16_t* Bt,
                                          int brow, int bcol, int lda, int ldb, int kb) {
        char* As = buf;
        char* Bs = buf + 16384;
#pragma unroll
        for (int p = 0; p < 4; ++p) {
            int ci = wid * 4 + p;
            gload16((const char*)A + ((size_t)(brow + arow[p]) * lda + kb) * 2 + ascb[p],
                    As + ci * 1024);
            gload16((const char*)Bt + ((size_t)(bcol + arow[p]) * ldb + kb) * 2 + ascb[p],
                    Bs + ci * 1024);
        }
    }
    __device__ __forceinline__ void compute(const char* buf, f32x4 (&acc)[4][4]) {
        const char* As = buf;
        const char* Bs = buf + 16384;
#pragma unroll
        for (int kc = 0; kc < 2; ++kc) {
            fp16x8 af[4], bfr[4];
            int boff = kc * 64 + hi * 16;
#pragma unroll
            for (int m = 0; m < 4; ++m) {
                int row = wr + m * 16 + lo;
                af[m] = *(const fp16x8*)(As + row * 128 + (boff ^ ((row & 7) << 4)));
            }
#pragma unroll
            for (int n = 0; n < 4; ++n) {
                int row = wc + n * 16 + lo;
                bfr[n] = *(const fp16x8*)(Bs + row * 128 + (boff ^ ((row & 7) << 4)));
            }
#pragma unroll
            for (int m = 0; m < 4; ++m)
#pragma unroll
                for (int n = 0; n < 4; ++n)
                    acc[m][n] = __builtin_amdgcn_mfma_f32_16x16x32_f16(af[m], bfr[n], acc[m][n], 0, 0, 0);
        }
    }
};

// qkv GEMM (b<384, flattened) + wo/w1/w3/w2 transposes (b>=384) in ONE dispatch.
__global__ __launch_bounds__(256, 2) void gemm_qkv_tr(const fp16_t* __restrict__ A,
                                                      const fp16_t* __restrict__ Bt,
                                                      fp16_t* __restrict__ Cout,
                                                      fp16_t* __restrict__ vT,
                                                      int M, int N, int K,
                                                      const float* __restrict__ wo,
                                                      const float* __restrict__ w1,
                                                      const float* __restrict__ w3,
                                                      const float* __restrict__ w2,
                                                      fp16_t* __restrict__ woT,
                                                      fp16_t* __restrict__ w1T,
                                                      fp16_t* __restrict__ w3T,
                                                      fp16_t* __restrict__ w2T) {
    __shared__ __align__(16) char smem[2][32768];
    int b = blockIdx.x;
    if (b >= 384) {
        int r = b - 384;
        if (r < 1024) {
            int bx = r % 32, by = r / 32;
            tr_tile_s((char*)smem, wo, 2048, by * 64, bx * 64, woT, 2048, bx * 64);
        } else if (r < 3840) {
            r -= 1024;
            int bx = r % 88, by = r / 88;
            tr_tile_s((char*)smem, w1, 5632, by * 64, bx * 64, w1T, 2048, bx * 64);
        } else if (r < 6656) {
            r -= 3840;
            int bx = r % 88, by = r / 88;
            tr_tile_s((char*)smem, w3, 5632, by * 64, bx * 64, w3T, 2048, bx * 64);
        } else {
            r -= 6656;
            int bx = r % 32, by = r / 32;
            tr_tile_s((char*)smem, w2, 2048, by * 64, bx * 64, w2T, 5632, bx * 64);
        }
        return;
    }

    int bx = b % 24, by = b / 24;
    GemmCore g;
    g.init(threadIdx.x);
    int brow = by * BM, bcol = bx * BN;
    int nK = K / BKK;

    f32x4 acc[4][4] = {};
    g.stage(smem[0], A, Bt, brow, bcol, K, K, 0);
    for (int kt = 0; kt < nK; ++kt) {
        if (kt + 1 < nK) {
            g.stage(smem[(kt + 1) & 1], A, Bt, brow, bcol, K, K, (kt + 1) * BKK);
            wait_vm8();
        } else {
            wait_vm0();
        }
        __builtin_amdgcn_s_barrier();
        __builtin_amdgcn_sched_barrier(0);
        g.compute(smem[kt & 1], acc);
        __builtin_amdgcn_s_barrier();
    }

    if (bx < 20) {
        float* sq = (float*)smem;
        bool isq = bx < 16;
#pragma unroll
        for (int m = 0; m < 4; ++m)
#pragma unroll
            for (int r = 0; r < 4; ++r) {
                float s = 0.f;
#pragma unroll
                for (int n = 0; n < 4; ++n) s += acc[m][n][r] * acc[m][n][r];
                s += __shfl_xor(s, 1); s += __shfl_xor(s, 2);
                s += __shfl_xor(s, 4); s += __shfl_xor(s, 8);
                if (g.lo == 0) sq[g.wid * 64 + m * 16 + g.hi * 4 + r] = s;
            }
        __syncthreads();
#pragma unroll
        for (int m = 0; m < 4; ++m)
#pragma unroll
            for (int r = 0; r < 4; ++r) {
                int rl = m * 16 + g.hi * 4 + r;
                float tot = sq[g.wid * 64 + rl] + sq[(g.wid ^ 1) * 64 + rl];
                float sc = rsqrtf(tot * (1.0f / 128.0f) + 1e-6f);
                if (isq) sc *= 0.08838834764831843f;
#pragma unroll
                for (int n = 0; n < 4; ++n) acc[m][n][r] *= sc;
            }
#pragma unroll
        for (int m = 0; m < 4; ++m) {
            int grow0 = brow + g.wr + m * 16 + g.hi * 4;
#pragma unroll
            for (int n = 0; n < 4; ++n) {
                int gcol = bcol + g.wc + n * 16 + g.lo;
#pragma unroll
                for (int r = 0; r < 4; ++r)
                    Cout[(size_t)(grow0 + r) * N + gcol] = (fp16_t)acc[m][n][r];
            }
        }
    } else {
        // v head: transposed write into vT [512][2048]. v region starts at col 2560.
#pragma unroll
        for (int m = 0; m < 4; ++m) {
            int gcol0 = brow + g.wr + m * 16 + g.hi * 4;
#pragma unroll
            for (int n = 0; n < 4; ++n) {
                int vrow = bcol + g.wc + n * 16 + g.lo - 2560;
                fp16x4 o = { (fp16_t)acc[m][n][0], (fp16_t)acc[m][n][1],
                             (fp16_t)acc[m][n][2], (fp16_t)acc[m][n][3] };
                *(fp16x4*)&vT[(size_t)vrow * 2048 + gcol0] = o;
            }
        }
    }
}

// BN=64 GEMM with fused residual epilogue (pipelined: vmcnt(6) + raw barriers).
__global__ __launch_bounds__(256, 2) void gemm_bt64_resid(const fp16_t* __restrict__ A,
                                                          const fp16_t* __restrict__ Bt,
                                                          float* __restrict__ Cout,
                                                          const float* __restrict__ resid,
                                                          int M, int N, int K) {
    __shared__ __align__(16) char smem[2][24576];  // A 16K | B 8K
    int tid = threadIdx.x, lane = tid & 63, wid = tid >> 6;
    int lo = lane & 15, hi = lane >> 4;
    int wr = (wid >> 1) * 64, wc = (wid & 1) * 32;
    int brow = blockIdx.y * 128, bcol = blockIdx.x * 64;
    int nK = K / BKK;

    int arow[4], ascb[4];
#pragma unroll
    for (int p = 0; p < 4; ++p) {
        int idx = (wid * 4 + p) * 64 + lane;
        int row = idx >> 3;
        int cb = (idx & 7) << 4;
        arow[p] = row;
        ascb[p] = cb ^ ((row & 7) << 4);
    }
    int brow_[2], bscb[2];
#pragma unroll
    for (int p = 0; p < 2; ++p) {
        int idx = (wid * 2 + p) * 64 + lane;
        int row = idx >> 3;
        int cb = (idx & 7) << 4;
        brow_[p] = row;
        bscb[p] = cb ^ ((row & 7) << 4);
    }

    auto stage = [&](char* buf, int kb) {
        char* As = buf;
        char* Bs = buf + 16384;
#pragma unroll
        for (int p = 0; p < 4; ++p)
            gload16((const char*)A + ((size_t)(brow + arow[p]) * K + kb) * 2 + ascb[p],
                    As + (wid * 4 + p) * 1024);
#pragma unroll
        for (int p = 0; p < 2; ++p)
            gload16((const char*)Bt + ((size_t)(bcol + brow_[p]) * K + kb) * 2 + bscb[p],
                    Bs + (wid * 2 + p) * 1024);
    };

    f32x4 acc[4][2] = {};
    stage(smem[0], 0);
    for (int kt = 0; kt < nK; ++kt) {
        if (kt + 1 < nK) {
            stage(smem[(kt + 1) & 1], (kt + 1) * BKK);
            wait_vm6();
        } else {
            wait_vm0();
        }
        __builtin_amdgcn_s_barrier();
        __builtin_amdgcn_sched_barrier(0);
        const char* As = smem[kt & 1];
        const char* Bs = As + 16384;
#pragma unroll
        for (int kc = 0; kc < 2; ++kc) {
            fp16x8 af[4], bfr[2];
            int boff = kc * 64 + hi * 16;
#pragma unroll
            for (int m = 0; m < 4; ++m) {
                int row = wr + m * 16 + lo;
                af[m] = *(const fp16x8*)(As + row * 128 + (boff ^ ((row & 7) << 4)));
            }
#pragma unroll
            for (int n = 0; n < 2; ++n) {
                int row = wc + n * 16 + lo;
                bfr[n] = *(const fp16x8*)(Bs + row * 128 + (boff ^ ((row & 7) << 4)));
            }
#pragma unroll
            for (int m = 0; m < 4; ++m)
#pragma unroll
                for (int n = 0; n < 2; ++n)
                    acc[m][n] = __builtin_amdgcn_mfma_f32_16x16x32_f16(af[m], bfr[n], acc[m][n], 0, 0, 0);
        }
        __builtin_amdgcn_s_barrier();
    }

#pragma unroll
    for (int m = 0; m < 4; ++m) {
        int grow0 = brow + wr + m * 16 + hi * 4;
#pragma unroll
        for (int n = 0; n < 2; ++n) {
            int gcol = bcol + wc + n * 16 + lo;
#pragma unroll
            for (int r = 0; r < 4; ++r) {
                size_t gidx = (size_t)(grow0 + r) * N + gcol;
                Cout[gidx] = acc[m][n][r] + resid[gidx];
            }
        }
    }
}

// Fused FFN up, half-width dual-acc (pipelined: vmcnt(8) + raw barriers).
__global__ __launch_bounds__(256, 2) void gemm_u1u3_half(const fp16_t* __restrict__ A,
                                                         const fp16_t* __restrict__ Bt1,
                                                         const fp16_t* __restrict__ Bt3,
                                                         fp16_t* __restrict__ G,
                                                         int M, int N, int K) {
    __shared__ __align__(16) char smem[2][32768];  // A 16K | B1 8K | B3 8K
    int tid = threadIdx.x, lane = tid & 63, wid = tid >> 6;
    int lo = lane & 15, hi = lane >> 4;
    int wr = (wid >> 1) * 64, wc = (wid & 1) * 32;
    int brow = blockIdx.y * 128, bcol = blockIdx.x * 64;
    int nK = K / BKK;

    int arow[4], ascb[4];
#pragma unroll
    for (int p = 0; p < 4; ++p) {
        int idx = (wid * 4 + p) * 64 + lane;
        int row = idx >> 3;
        int cb = (idx & 7) << 4;
        arow[p] = row;
        ascb[p] = cb ^ ((row & 7) << 4);
    }
    int brow_[2], bscb[2];
#pragma unroll
    for (int p = 0; p < 2; ++p) {
        int idx = (wid * 2 + p) * 64 + lane;
        int row = idx >> 3;
        int cb = (idx & 7) << 4;
        brow_[p] = row;
        bscb[p] = cb ^ ((row & 7) << 4);
    }

    auto stage = [&](char* buf, int kb) {
        char* As = buf;
        char* B1s = buf + 16384;
        char* B3s = buf + 24576;
#pragma unroll
        for (int p = 0; p < 4; ++p)
            gload16((const char*)A + ((size_t)(brow + arow[p]) * K + kb) * 2 + ascb[p],
                    As + (wid * 4 + p) * 1024);
#pragma unroll
        for (int p = 0; p < 2; ++p) {
            gload16((const char*)Bt1 + ((size_t)(bcol + brow_[p]) * K + kb) * 2 + bscb[p],
                    B1s + (wid * 2 + p) * 1024);
            gload16((const char*)Bt3 + ((size_t)(bcol + brow_[p]) * K + kb) * 2 + bscb[p],
                    B3s + (wid * 2 + p) * 1024);
        }
    };

    f32x4 acc1[4][2] = {}, acc3[4][2] = {};
    stage(smem[0], 0);
    for (int kt = 0; kt < nK; ++kt) {
        if (kt + 1 < nK) {
            stage(smem[(kt + 1) & 1], (kt + 1) * BKK);
            wait_vm8();
        } else {
            wait_vm0();
        }
        __builtin_amdgcn_s_barrier();
        __builtin_amdgcn_sched_barrier(0);
        const char* As = smem[kt & 1];
        const char* B1s = As + 16384;
        const char* B3s = As + 24576;
#pragma unroll
        for (int kc = 0; kc < 2; ++kc) {
            fp16x8 af[4], b1f[2], b3f[2];
            int boff = kc * 64 + hi * 16;
#pragma unroll
            for (int m = 0; m < 4; ++m) {
                int row = wr + m * 16 + lo;
                af[m] = *(const fp16x8*)(As + row * 128 + (boff ^ ((row & 7) << 4)));
            }
#pragma unroll
            for (int n = 0; n < 2; ++n) {
                int row = wc + n * 16 + lo;
                int o = row * 128 + (boff ^ ((row & 7) << 4));
                b1f[n] = *(const fp16x8*)(B1s + o);
                b3f[n] = *(const fp16x8*)(B3s + o);
            }
#pragma unroll
            for (int m = 0; m < 4; ++m)
#pragma unroll
                for (int n = 0; n < 2; ++n) {
                    acc1[m][n] = __builtin_amdgcn_mfma_f32_16x16x32_f16(af[m], b1f[n], acc1[m][n], 0, 0, 0);
                    acc3[m][n] = __builtin_amdgcn_mfma_f32_16x16x32_f16(af[m], b3f[n], acc3[m][n], 0, 0, 0);
                }
        }
        __builtin_amdgcn_s_barrier();
    }

#pragma unroll
    for (int m = 0; m < 4; ++m) {
        int grow0 = brow + wr + m * 16 + hi * 4;
#pragma unroll
        for (int n = 0; n < 2; ++n) {
            int gcol = bcol + wc + n * 16 + lo;
#pragma unroll
            for (int r = 0; r < 4; ++r) {
                float u = acc1[m][n][r];
                float val = (u / (1.0f + __expf(-u))) * acc3[m][n][r];
                G[(size_t)(grow0 + r) * N + gcol] = (fp16_t)val;
            }
        }
    }
}

// ---------------- Flash attention (standalone, 512 blocks, pipelined) ----------------
__global__ __launch_bounds__(256, 2) void attn_kernel(const fp16_t* __restrict__ qkv,
                                                      const fp16_t* __restrict__ vT,
                                                      fp16_t* __restrict__ o) {
    __shared__ __align__(16) char smem[2 * 32768 + 4 * 2304];
    char* Ps = smem + 65536;

    int t = blockIdx.x, qh = blockIdx.y;
    int kvh = qh >> 2;
    int qs = t * 64;
    int tid = threadIdx.x, lane = tid & 63, wid = tid >> 6;
    int lo = lane & 15, hi = lane >> 4;

    fp16x8 qf[4];
    {
        const fp16_t* qptr = qkv + (size_t)(qs + wid * 16 + lo) * 3072 + qh * 128 + hi * 8;
#pragma unroll
        for (int kc = 0; kc < 4; ++kc) qf[kc] = *(const fp16x8*)(qptr + kc * 32);
    }

    f32x4 oacc[8] = {};
    float m_r[4], l_r[4];
#pragma unroll
    for (int r = 0; r < 4; ++r) { m_r[r] = -1e30f; l_r[r] = 0.0f; }

    int lot = qs - (WIN - 1);
    int jt_lo = lot <= 0 ? 0 : (lot >> 6);
    int nt = (jt_lo > 0) ? (t - jt_lo + 2) : (t + 1);

    int kci = wid * 4, idxb = lane;
    auto stagekv = [&](char* buf, int js) {
        char* Ks = buf;
        char* VTs = buf + 16384;
#pragma unroll
        for (int p = 0; p < 4; ++p) {
            int ci = kci + p;
            int idx = ci * 64 + idxb;
            int krow = idx >> 4;
            int kcb = (idx & 15) << 4;
            int kscb = kcb ^ ((krow & 7) << 4);
            gload16((const char*)qkv + ((size_t)(js + krow) * 3072 + 2048 + kvh * 128) * 2 + kscb,
                    Ks + ci * 1024);
            int vrow = idx >> 3;
            int vcb = (idx & 7) << 4;
            int vscb = vcb ^ ((vrow & 7) << 4);
            gload16((const char*)vT + ((size_t)(kvh * 128 + vrow) * 2048 + js) * 2 + vscb,
                    VTs + ci * 1024);
        }
    };
    auto jt_of = [&](int ti) { return (jt_lo > 0) ? (ti == 0 ? 0 : jt_lo + ti - 1) : ti; };

    stagekv(smem, jt_of(0) * 64);

    for (int ti = 0; ti < nt; ++ti) {
        if (ti + 1 < nt) {
            stagekv(smem + ((ti + 1) & 1) * 32768, jt_of(ti + 1) * 64);
            wait_vm8();
        } else {
            wait_vm0();
        }
        __builtin_amdgcn_s_barrier();
        __builtin_amdgcn_sched_barrier(0);

        char* Ks = smem + (ti & 1) * 32768;
        char* VTs = Ks + 16384;
        int jt = jt_of(ti);
        int js = jt * 64;

        f32x4 s[4] = {};
        __builtin_amdgcn_s_setprio(1);
#pragma unroll
        for (int kc = 0; kc < 4; ++kc) {
#pragma unroll
            for (int jc = 0; jc < 4; ++jc) {
                int row = jc * 16 + lo;
                fp16x8 kf = *(const fp16x8*)(Ks + row * 256 + ((kc * 64 + hi * 16) ^ ((row & 7) << 4)));
                s[jc] = __builtin_amdgcn_mfma_f32_16x16x32_f16(qf[kc], kf, s[jc], 0, 0, 0);
            }
        }
        __builtin_amdgcn_s_setprio(0);

        float mt[4] = { -1e30f, -1e30f, -1e30f, -1e30f };
        bool full = (jt < t) && !((t >= 9) && (jt == t - 8));
        if (full) {
#pragma unroll
            for (int jc = 0; jc < 4; ++jc)
#pragma unroll
                for (int r = 0; r < 4; ++r) mt[r] = fmaxf(mt[r], s[jc][r]);
        } else {
#pragma unroll
            for (int jc = 0; jc < 4; ++jc) {
                int j = js + jc * 16 + lo;
#pragma unroll
                for (int r = 0; r < 4; ++r) {
                    int i = qs + wid * 16 + hi * 4 + r;
                    bool ok = (j <= i) && (((i - j) < WIN) || (j < NG) || (i < NG));
                    float sv = ok ? s[jc][r] : -1e30f;
                    s[jc][r] = sv;
                    mt[r] = fmaxf(mt[r], sv);
                }
            }
        }
#pragma unroll
        for (int m2 = 1; m2 <= 8; m2 <<= 1)
#pragma unroll
            for (int r = 0; r < 4; ++r) mt[r] = fmaxf(mt[r], __shfl_xor(mt[r], m2));
        float sf[4], psum[4];
#pragma unroll
        for (int r = 0; r < 4; ++r) {
            float mn = fmaxf(m_r[r], mt[r]);
            sf[r] = __expf(m_r[r] - mn);
            m_r[r] = mn;
            psum[r] = 0.0f;
        }
#pragma unroll
        for (int jc = 0; jc < 4; ++jc)
#pragma unroll
            for (int r = 0; r < 4; ++r) {
                float p = __expf(s[jc][r] - m_r[r]);
                s[jc][r] = p;
                psum[r] += p;
            }
#pragma unroll
        for (int m2 = 1; m2 <= 8; m2 <<= 1)
#pragma unroll
            for (int r = 0; r < 4; ++r) psum[r] += __shfl_xor(psum[r], m2);
#pragma unroll
        for (int r = 0; r < 4; ++r) l_r[r] = l_r[r] * sf[r] + psum[r];
#pragma unroll
        for (int nc = 0; nc < 8; ++nc)
#pragma unroll
            for (int r = 0; r < 4; ++r) oacc[nc][r] *= sf[r];

        char* Pb = Ps + wid * 2304;
#pragma unroll
        for (int jc = 0; jc < 4; ++jc)
#pragma unroll
            for (int r = 0; r < 4; ++r)
                *(fp16_t*)(Pb + (hi * 4 + r) * 144 + (jc * 16 + lo) * 2) = (fp16_t)s[jc][r];
        fp16x8 pa[2];
#pragma unroll
        for (int jc2 = 0; jc2 < 2; ++jc2)
            pa[jc2] = *(const fp16x8*)(Pb + lo * 144 + jc2 * 64 + hi * 16);

        __builtin_amdgcn_s_setprio(1);
#pragma unroll
        for (int jc2 = 0; jc2 < 2; ++jc2)
#pragma unroll
            for (int nc = 0; nc < 8; ++nc) {
                int row = nc * 16 + lo;
                fp16x8 vf = *(const fp16x8*)(VTs + row * 128 + ((jc2 * 64 + hi * 16) ^ ((row & 7) << 4)));
                oacc[nc] = __builtin_amdgcn_mfma_f32_16x16x32_f16(pa[jc2], vf, oacc[nc], 0, 0, 0);
            }
        __builtin_amdgcn_s_setprio(0);

        __builtin_amdgcn_s_barrier();
    }

#pragma unroll
    for (int r = 0; r < 4; ++r) {
        float inv = 1.0f / l_r[r];
        int orow = qs + wid * 16 + hi * 4 + r;
#pragma unroll
        for (int nc = 0; nc < 8; ++nc)
            o[(size_t)orow * 2048 + qh * 128 + nc * 16 + lo] = (fp16_t)(oacc[nc][r] * inv);
    }
}

// ---------------- host ----------------
extern "C" void kernel_launch(void* const* d_in, const int* in_sizes, int n_in,
                              void* d_out, int out_size, void* d_ws, size_t ws_size,
                              hipStream_t stream) {
    // setup_inputs() dict order: x, g_attn, g_ffn, wq, wk, wv, wo, w1, w3, w2
    const float* x = (const float*)d_in[0];
    const float* g_attn = (const float*)d_in[1];
    const float* g_ffn = (const float*)d_in[2];
    const float* wq = (const float*)d_in[3];
    const float* wk = (const float*)d_in[4];
    const float* wv = (const float*)d_in[5];
    const float* wo = (const float*)d_in[6];
    const float* w1 = (const float*)d_in[7];  // gate proj (D,F)
    const float* w3 = (const float*)d_in[8];  // up proj   (D,F)  <- dict order!
    const float* w2 = (const float*)d_in[9];  // down proj (F,D)  <- dict order!
    float* out = (float*)d_out;               // doubles as x1 buffer

    char* ws = (char*)d_ws;
    size_t off = 0;
    auto alloc = [&](size_t bytes) {
        char* p = ws + off;
        off += (bytes + 255) & ~(size_t)255;
        return p;
    };
    fp16_t* hbuf  = (fp16_t*)alloc(2048ull * 2048 * 2);  // h, then attn out o
    fp16_t* wqkvT = (fp16_t*)alloc(3072ull * 2048 * 2);
    fp16_t* woT   = (fp16_t*)alloc(2048ull * 2048 * 2);
    fp16_t* vTb   = (fp16_t*)alloc(512ull * 2048 * 2);
    fp16_t* qkv   = (fp16_t*)alloc(2048ull * 3072 * 2);  // q|k (v direct to vTb), then h2
    fp16_t* gbuf  = (fp16_t*)alloc(2048ull * 5632 * 2);  // g = silu(u1)*u3
    fp16_t* w1T   = (fp16_t*)alloc(5632ull * 2048 * 2);
    fp16_t* w3T   = (fp16_t*)alloc(5632ull * 2048 * 2);
    fp16_t* w2T   = (fp16_t*)alloc(2048ull * 5632 * 2);
    if (off > ws_size) {  // diagnostic fallback: absmax ~= max|ref|
        hipMemsetAsync(d_out, 0, (size_t)out_size * 4, stream);
        return;
    }

    // prep: qkv-weight transpose + h = RMSNorm(x)*g_attn (one dispatch)
    prep_kernel<<<3584, 256, 0, stream>>>(wq, wk, wv, wqkvT, x, g_attn, hbuf);
    // qkv GEMM (384 blocks) co-scheduled with wo/w1/w3/w2 transposes
    gemm_qkv_tr<<<9856, 256, 0, stream>>>(hbuf, wqkvT, qkv, vTb, 2048, 3072, 2048,
                                          wo, w1, w3, w2, woT, w1T, w3T, w2T);
    // attention -> o (reuses hbuf)
    attn_kernel<<<dim3(32, 16), 256, 0, stream>>>(qkv, vTb, hbuf);
    // x1 = x + o @ wo  (BN=64, 512 blocks, fused residual, fp32 -> d_out)
    gemm_bt64_resid<<<dim3(32, 16), 256, 0, stream>>>(hbuf, woT, out, x, 2048, 2048, 2048);
    // h2 = RMSNorm(x1) * g_ffn  (-> qkv buffer)
    rmsnorm_kernel<<<2048, 256, 0, stream>>>(out, g_ffn, qkv);
    // g = silu(h2@w1) * (h2@w3), half-width dual-acc fusion (1408 blocks)
    gemm_u1u3_half<<<dim3(88, 16), 256, 0, stream>>>(qkv, w1T, w3T, gbuf, 2048, 5632, 2048);
    // out = x1 + g @ w2  (BN=64, 512 blocks, fused residual, in-place on d_out)
    gemm_bt64_resid<<<dim3(32, 16), 256, 0, stream>>>(gbuf, w2T, out, out, 2048, 2048, 5632);
}